// Round 5
// baseline (1409.520 us; speedup 1.0000x reference)
//
#include <hip/hip_runtime.h>

#define BB 512
#define TT 1024
#define HH 100
#define VV 62
#define BTV (512*1024*62)

// ws float offsets (buf = ws[0 .. 52428800) = [B][T][H] fp32)
#define OFF_EP  52428800   // 62*100 ep table (emb@Wi0^T + b0)   [6200]
#define OFF_WU  52435200   // unit weights: u0 100*112, u1 200*112, u2 200*112  [56000]
#define OFF_BS  52491200   // bias sums layers 1,2: [2][100]
#define OFF_WDT 52491400   // W_dec transposed+padded: [100][64]
#define OFF_BDP 52497800   // b_dec padded to 64

typedef float v2f __attribute__((ext_vector_type(2)));
typedef float v4f __attribute__((ext_vector_type(4)));

__device__ inline float tanh_fast(float x){
  float ax = fabsf(x);
  float e  = __expf(2.0f*ax);
  float r  = 1.0f - __fdividef(2.0f, e + 1.0f);
  return copysignf(r, x);
}

__device__ inline float dpp_xor1(float x){
  return __int_as_float(__builtin_amdgcn_update_dpp(0, __float_as_int(x), 0xB1, 0xF, 0xF, true));
}
__device__ inline float dpp_xor2(float x){
  return __int_as_float(__builtin_amdgcn_update_dpp(0, __float_as_int(x), 0x4E, 0xF, 0xF, true));
}
__device__ inline float swz_xor4(float x){
  return __int_as_float(__builtin_amdgcn_ds_swizzle(__float_as_int(x), 0x101F));
}

// transpose-reduce across an aligned quad: lane q ends with sum over quad of a[q]
__device__ inline float quad_txr(float a0,float a1,float a2,float a3,bool odd,bool hi){
  float s01 = odd ? a0 : a1, k01 = odd ? a1 : a0;
  float A  = k01 + dpp_xor1(s01);
  float s23 = odd ? a2 : a3, k23 = odd ? a3 : a2;
  float Bq = k23 + dpp_xor1(s23);
  float sAB = hi ? A : Bq, kAB = hi ? Bq : A;
  return kAB + dpp_xor2(sAB);
}

__global__ void prep_kernel(
    const float* __restrict__ emb, const float* __restrict__ W_ih,
    const float* __restrict__ W_hh,
    const float* __restrict__ b_ih, const float* __restrict__ b_hh,
    const float* __restrict__ W_dec, const float* __restrict__ b_dec,
    float* __restrict__ ws)
{
  int g = blockIdx.x*256 + threadIdx.x;
  if (g < 6200){
    int v = g/100, k = g%100;
    float a = b_ih[k] + b_hh[k];
    const float* er = emb + v*100;
    const float* wr = W_ih + k*100;
    for (int h=0; h<100; h++) a = fmaf(er[h], wr[h], a);
    ws[OFF_EP + v*100 + k] = a;
  } else if (g < 62200){
    int i = g - 6200;                 // [0,56000)
    int u, base;
    if (i < 11200){ u=0; base=i; }
    else if (i < 33600){ u=1; base=i-11200; }
    else { u=2; base=i-33600; }
    int lane = base/112, e = base%112;
    int j = e/28, c = e%28;           // row-in-quad, col-in-chunk
    float val;
    if (u==0){
      int gq = lane&3, rp = lane>>2;
      int row = 4*rp + j, col = 28*gq + c;
      val = (col < HH) ? W_hh[row*HH + col] : 0.f;
    } else {
      int gq = lane&7, rp = lane>>3;
      int row = 4*rp + j, col = 28*(gq&3) + c;
      const float* M = (gq < 4) ? W_ih : W_hh;
      val = (col < HH) ? M[u*10000 + row*HH + col] : 0.f;
    }
    ws[OFF_WU + i] = val;
  } else if (g < 62400){
    int i = g - 62200;
    int l = i/100 + 1, k = i%100;
    ws[OFF_BS + i] = b_ih[l*100+k] + b_hh[l*100+k];
  } else if (g < 68800){
    int i = g - 62400;
    int h = i/64, v = i%64;
    ws[OFF_WDT + i] = (v < VV) ? W_dec[v*100 + h] : 0.f;
  } else if (g < 68864){
    int i = g - 68800;
    ws[OFF_BDP + i] = (i < VV) ? b_dec[i] : 0.f;
  }
}

// Fused 3-layer pipelined recurrence, 4-rows x 28-cols per lane.
// u0: tid 0-99   (L0): gq=l&3, rp=l>>2; rows 4rp+{0..3}, cols [28gq,28gq+28) of Wh0.
// u1: tid 104-303 (L1): gq=l&7, rp=l>>3; gq<4 -> Wi1 chunk (reads h0), gq>=4 -> Wh1 (reads h1).
// u2: tid 304-503 (L2): same with Wi2 (reads h1) / Wh2 (reads h2); also stores to buf.
// One barrier per step; double-buffered h parity. Stores fire-and-forget.
// Weights are loaded via VOLATILE inline-asm global_load_dwordx4: a volatile asm
// definition cannot be rematerialized/duplicated by LLVM, so the 112 floats stay
// register-resident across the serial loop. (r3/r4: plain loads + "+v" pins left
// VGPR_Count=84 -> compiler reloaded weights from L2 inside every step.)
__global__ __launch_bounds__(512, 2) void fused_rnn(
    const int* __restrict__ ids, const float* __restrict__ ws,
    float* __restrict__ buf, float* __restrict__ hid)
{
  __shared__ float ep_s[6200];
  __shared__ int   ids_s[2][TT];
  __shared__ float hs[2][2][3][112];   // [parity][batch][layer][paddedH]

  const int tid = threadIdx.x;
  const int bA = blockIdx.x, bB = blockIdx.x + 256;

  int u, l; bool act;
  if      (tid < 100){ u=0; l=tid;     act=true;  }
  else if (tid < 104){ u=0; l=tid-4;   act=false; }   // idle quad (aligned)
  else if (tid < 304){ u=1; l=tid-104; act=true;  }   // 104 = 8*13: oct-aligned
  else if (tid < 504){ u=2; l=tid-304; act=true;  }   // 304 = 8*38
  else               { u=2; l=tid-312; act=false; }   // idle oct (aligned)

  int gq, rp, g3, lv;
  if (u==0){ gq = l&3; rp = l>>2; g3 = gq; lv = 0; }
  else     { gq = l&7; rp = l>>3; g3 = gq&3; lv = (u==1) ? (gq<4?0:1) : (gq<4?1:2); }
  const int r = 4*rp + g3;                 // output row owned after reduce
  const bool odd = tid & 1, hi = tid & 2;

  // per-lane weights: 4 rows x 28 cols = 28 float4 (112 VGPRs), j-major.
  // Volatile asm loads -> non-rematerializable -> must stay in VGPRs.
  v4f w4[28];
  {
    int ubase = (u==0) ? 0 : (u==1) ? 11200 : 33600;
    const float* wp = ws + OFF_WU + ubase + l*112;
    #pragma unroll
    for (int i=0;i<28;i++){
      asm volatile("global_load_dwordx4 %0, %1, off"
                   : "=v"(w4[i]) : "v"(wp + 4*i) : "memory");
    }
    asm volatile("s_waitcnt vmcnt(0)" ::: "memory");
  }
  const float br = (u==0) ? 0.f : ws[OFF_BS + (u-1)*100 + r];

  for (int i=tid;i<6200;i+=512) ep_s[i] = ws[OFF_EP+i];
  for (int i=tid;i<TT;i+=512){
    ids_s[0][i] = ids[(size_t)bA*TT + i];
    ids_s[1][i] = ids[(size_t)bB*TT + i];
  }
  for (int i=tid;i<2*2*3*112;i+=512) ((float*)hs)[i] = 0.f;
  __syncthreads();

  // read bases (float4 units): [(p*2+X)*3+lv]*28 + 7*g3 ; parity stride 168
  const float4* h4 = (const float4*)hs;
  const int iA = lv*28 + 7*g3;
  const int iB = 84 + lv*28 + 7*g3;
  float* hw = (float*)hs;

  int idnA = 0, idnB = 0; float epxA = 0.f, epxB = 0.f;
  if (u == 0){
    epxA = ep_s[ids_s[0][0]*HH + l];
    epxB = ep_s[ids_s[1][0]*HH + l];
    idnA = ids_s[0][1]; idnB = ids_s[1][1];
  }
  const int X  = gq >> 2;                  // batch handled in epilogue (u1/u2)
  const int bX = X ? bB : bA;
  float* stp = buf + (size_t)bX*TT*HH + r; // [B][T][H]

  for (int s = 0; s < TT + 2; ++s){
    const int po = (s & 1) ? 0 : 168;      // read parity offset (float4)
    const int wo = (s & 1) ? 672 : 0;      // write parity offset (float)

    v2f aA0={0.f,0.f}, aA1={0.f,0.f}, aA2={0.f,0.f}, aA3={0.f,0.f};
    v2f aB0={0.f,0.f}, aB1={0.f,0.f}, aB2={0.f,0.f}, aB3={0.f,0.f};
    const float4* pA = h4 + (iA + po);
    const float4* pB = h4 + (iB + po);
    #pragma unroll
    for (int i=0;i<7;i++){
      float4 ha = pA[i];
      float4 hb = pB[i];
      v2f h0 = {ha.x,ha.y}, h1 = {ha.z,ha.w};
      v2f g0 = {hb.x,hb.y}, g1 = {hb.z,hb.w};
      v4f wv0 = w4[i], wv1 = w4[7+i], wv2 = w4[14+i], wv3 = w4[21+i];
      v2f w00={wv0.x,wv0.y}, w01={wv0.z,wv0.w};
      v2f w10={wv1.x,wv1.y}, w11={wv1.z,wv1.w};
      v2f w20={wv2.x,wv2.y}, w21={wv2.z,wv2.w};
      v2f w30={wv3.x,wv3.y}, w31={wv3.z,wv3.w};
      aA0 = __builtin_elementwise_fma(w00,h0,aA0); aA0 = __builtin_elementwise_fma(w01,h1,aA0);
      aA1 = __builtin_elementwise_fma(w10,h0,aA1); aA1 = __builtin_elementwise_fma(w11,h1,aA1);
      aA2 = __builtin_elementwise_fma(w20,h0,aA2); aA2 = __builtin_elementwise_fma(w21,h1,aA2);
      aA3 = __builtin_elementwise_fma(w30,h0,aA3); aA3 = __builtin_elementwise_fma(w31,h1,aA3);
      aB0 = __builtin_elementwise_fma(w00,g0,aB0); aB0 = __builtin_elementwise_fma(w01,g1,aB0);
      aB1 = __builtin_elementwise_fma(w10,g0,aB1); aB1 = __builtin_elementwise_fma(w11,g1,aB1);
      aB2 = __builtin_elementwise_fma(w20,g0,aB2); aB2 = __builtin_elementwise_fma(w21,g1,aB2);
      aB3 = __builtin_elementwise_fma(w30,g0,aB3); aB3 = __builtin_elementwise_fma(w31,g1,aB3);
    }
    float zA = quad_txr(aA0.x+aA0.y, aA1.x+aA1.y, aA2.x+aA2.y, aA3.x+aA3.y, odd, hi);
    float zB = quad_txr(aB0.x+aB0.y, aB1.x+aB1.y, aB2.x+aB2.y, aB3.x+aB3.y, odd, hi);
    if (u){
      zA += swz_xor4(zA);
      zB += swz_xor4(zB);
    }

    if (u == 0){
      if (act && s < TT){
        float hA = tanh_fast(epxA + zA);
        float hB = tanh_fast(epxB + zB);
        hw[wo + l]       = hA;             // [p][A][0][l]
        hw[wo + 336 + l] = hB;             // [p][B][0][l]
        if (s == TT-1){
          hid[(size_t)bA*HH + l] = hA;
          hid[(size_t)bB*HH + l] = hB;
        }
        epxA = ep_s[idnA*HH + l];
        epxB = ep_s[idnB*HH + l];
        int nid = (s+2 < TT) ? s+2 : TT-1;
        idnA = ids_s[0][nid]; idnB = ids_s[1][nid];
      }
    } else {
      float z = X ? zB : zA;
      bool on = (u == 1) ? ((unsigned)(s-1) < TT) : (s >= 2);
      if (act && on){
        float hv = tanh_fast(z + br);
        hw[wo + X*336 + u*112 + r] = hv;   // [p][X][u][r]
        if (u == 2){ *stp = hv; stp += HH; }
        if (u == 1 && s == TT)     hid[((size_t)BB   + bX)*HH + r] = hv;
        if (u == 2 && s == TT+1)   hid[((size_t)2*BB + bX)*HH + r] = hv;
      }
    }

    asm volatile("s_waitcnt lgkmcnt(0)" ::: "memory");
    __builtin_amdgcn_s_barrier();
    asm volatile("" ::: "memory");
  }
}

// Decoder: WG = (b, 128 consecutive t). buf is [B][T][H] -> fully linear reads.
__global__ __launch_bounds__(128) void dec_kernel(
    const float* __restrict__ buf, const float* __restrict__ wdt,
    const float* __restrict__ bdp, float* __restrict__ out)
{
  __shared__ float rt[100*129];
  const int tid = threadIdx.x;
  const int wg  = blockIdx.x;
  const int bb  = wg >> 3;
  const int t0  = (wg & 7) * 128;
  const float4* b4 = (const float4*)buf;
  const size_t rb = ((size_t)bb*TT + t0)*25;

  #pragma unroll
  for (int j=0;j<25;j++){
    int f = j*128 + tid;
    int i = f/25, c = f%25;
    float4 v = b4[rb + f];
    rt[(4*c+0)*129 + i] = v.x;
    rt[(4*c+1)*129 + i] = v.y;
    rt[(4*c+2)*129 + i] = v.z;
    rt[(4*c+3)*129 + i] = v.w;
  }
  __syncthreads();

  v4f acc[16];
  const v4f* bd4 = (const v4f*)bdp;
  #pragma unroll
  for (int j=0;j<16;j++) acc[j] = bd4[j];

  for (int h=0; h<HH; h++){
    float rv = rt[h*129 + tid];
    v4f rv4 = {rv, rv, rv, rv};
    const v4f* w4g = (const v4f*)(wdt + h*64);
    #pragma unroll
    for (int j=0;j<16;j++) acc[j] = __builtin_elementwise_fma(w4g[j], rv4, acc[j]);
  }

  float2* o2 = (float2*)(out + ((size_t)bb*TT + t0 + tid)*VV);
  #pragma unroll
  for (int j=0;j<15;j++){
    o2[2*j]   = make_float2(acc[j].x, acc[j].y);
    o2[2*j+1] = make_float2(acc[j].z, acc[j].w);
  }
  o2[30] = make_float2(acc[15].x, acc[15].y);   // v=60,61
}

extern "C" void kernel_launch(void* const* d_in, const int* in_sizes, int n_in,
                              void* d_out, int out_size, void* d_ws, size_t ws_size,
                              hipStream_t stream)
{
  const int*   ids   = (const int*)d_in[0];
  const float* emb   = (const float*)d_in[1];
  const float* W_ih  = (const float*)d_in[2];
  const float* W_hh  = (const float*)d_in[3];
  const float* b_ih  = (const float*)d_in[4];
  const float* b_hh  = (const float*)d_in[5];
  const float* W_dec = (const float*)d_in[6];
  const float* b_dec = (const float*)d_in[7];
  float* out = (float*)d_out;
  float* ws  = (float*)d_ws;
  float* buf = ws;                 // [B][T][H] fp32, ~210 MB
  float* hid = out + BTV;

  prep_kernel<<<269, 256, 0, stream>>>(emb, W_ih, W_hh, b_ih, b_hh, W_dec, b_dec, ws);
  fused_rnn <<<256, 512, 0, stream>>>(ids, ws, buf, hid);
  dec_kernel<<<4096, 128, 0, stream>>>(buf, ws+OFF_WDT, ws+OFF_BDP, out);
}

// Round 6
// 1362.365 us; speedup vs baseline: 1.0346x; 1.0346x over previous
//
#include <hip/hip_runtime.h>

#define BB 512
#define TT 1024
#define HH 100
#define VV 62
#define BTV (512*1024*62)

// ws float offsets (buf = ws[0 .. 52428800) = [B][T][H] fp32)
#define OFF_EP  52428800   // 62*100 ep table (emb@Wi0^T + b0)   [6200]
#define OFF_WU  52435200   // unit weights: u0 100*112, u1 200*112, u2 200*112  [56000]
#define OFF_BS  52491200   // bias sums layers 1,2: [2][100]
#define OFF_WDT 52491400   // W_dec transposed+padded: [100][64]
#define OFF_BDP 52497800   // b_dec padded to 64

typedef float v2f __attribute__((ext_vector_type(2)));
typedef float v4f __attribute__((ext_vector_type(4)));

__device__ inline float tanh_fast(float x){
  float ax = fabsf(x);
  float e  = __expf(2.0f*ax);
  float r  = 1.0f - __fdividef(2.0f, e + 1.0f);
  return copysignf(r, x);
}

__device__ inline float dpp_xor1(float x){
  return __int_as_float(__builtin_amdgcn_update_dpp(0, __float_as_int(x), 0xB1, 0xF, 0xF, true));
}
__device__ inline float dpp_xor2(float x){
  return __int_as_float(__builtin_amdgcn_update_dpp(0, __float_as_int(x), 0x4E, 0xF, 0xF, true));
}
__device__ inline float swz_xor4(float x){
  return __int_as_float(__builtin_amdgcn_ds_swizzle(__float_as_int(x), 0x101F));
}

// transpose-reduce across an aligned quad: lane q ends with sum over quad of a[q]
__device__ inline float quad_txr(float a0,float a1,float a2,float a3,bool odd,bool hi){
  float s01 = odd ? a0 : a1, k01 = odd ? a1 : a0;
  float A  = k01 + dpp_xor1(s01);
  float s23 = odd ? a2 : a3, k23 = odd ? a3 : a2;
  float Bq = k23 + dpp_xor1(s23);
  float sAB = hi ? A : Bq, kAB = hi ? Bq : A;
  return kAB + dpp_xor2(sAB);
}

__global__ void prep_kernel(
    const float* __restrict__ emb, const float* __restrict__ W_ih,
    const float* __restrict__ W_hh,
    const float* __restrict__ b_ih, const float* __restrict__ b_hh,
    const float* __restrict__ W_dec, const float* __restrict__ b_dec,
    float* __restrict__ ws)
{
  int g = blockIdx.x*256 + threadIdx.x;
  if (g < 6200){
    int v = g/100, k = g%100;
    float a = b_ih[k] + b_hh[k];
    const float* er = emb + v*100;
    const float* wr = W_ih + k*100;
    for (int h=0; h<100; h++) a = fmaf(er[h], wr[h], a);
    ws[OFF_EP + v*100 + k] = a;
  } else if (g < 62200){
    int i = g - 6200;                 // [0,56000)
    int u, base;
    if (i < 11200){ u=0; base=i; }
    else if (i < 33600){ u=1; base=i-11200; }
    else { u=2; base=i-33600; }
    int lane = base/112, e = base%112;
    int j = e/28, c = e%28;           // row-in-quad, col-in-chunk
    float val;
    if (u==0){
      int gq = lane&3, rp = lane>>2;
      int row = 4*rp + j, col = 28*gq + c;
      val = (col < HH) ? W_hh[row*HH + col] : 0.f;
    } else {
      int gq = lane&7, rp = lane>>3;
      int row = 4*rp + j, col = 28*(gq&3) + c;
      const float* M = (gq < 4) ? W_ih : W_hh;
      val = (col < HH) ? M[u*10000 + row*HH + col] : 0.f;
    }
    ws[OFF_WU + i] = val;
  } else if (g < 62400){
    int i = g - 62200;
    int l = i/100 + 1, k = i%100;
    ws[OFF_BS + i] = b_ih[l*100+k] + b_hh[l*100+k];
  } else if (g < 68800){
    int i = g - 62400;
    int h = i/64, v = i%64;
    ws[OFF_WDT + i] = (v < VV) ? W_dec[v*100 + h] : 0.f;
  } else if (g < 68864){
    int i = g - 68800;
    ws[OFF_BDP + i] = (i < VV) ? b_dec[i] : 0.f;
  }
}

// Fused 3-layer pipelined recurrence, 4-rows x 28-cols per lane.
// u0: tid 0-99   (L0): gq=l&3, rp=l>>2; rows 4rp+{0..3}, cols [28gq,28gq+28) of Wh0.
// u1: tid 104-303 (L1): gq=l&7, rp=l>>3; gq<4 -> Wi1 chunk (reads h0), gq>=4 -> Wh1 (reads h1).
// u2: tid 304-503 (L2): same with Wi2 (reads h1) / Wh2 (reads h2); also stores to buf.
// One barrier per step; double-buffered h parity. Stores fire-and-forget.
//
// amdgpu_waves_per_eu(2,2): pin occupancy window to exactly 2 waves/EU so the
// register budget is 256/lane. With only a MINIMUM (launch_bounds 2nd arg), the
// allocator chased higher occupancy (VGPR_Count=84 in r3-r5) and spilled the
// 112-float weight block -> per-step spill-restore traffic dominated the loop.
// Grid is 256 WGs = 1 WG/CU = 8 waves/CU regardless, so extra occupancy is free.
__global__ __attribute__((amdgpu_waves_per_eu(2, 2))) __launch_bounds__(512)
void fused_rnn(
    const int* __restrict__ ids, const float* __restrict__ ws,
    float* __restrict__ buf, float* __restrict__ hid)
{
  __shared__ float ep_s[6200];
  __shared__ int   ids_s[2][TT];
  __shared__ float hs[2][2][3][112];   // [parity][batch][layer][paddedH]

  const int tid = threadIdx.x;
  const int bA = blockIdx.x, bB = blockIdx.x + 256;

  int u, l; bool act;
  if      (tid < 100){ u=0; l=tid;     act=true;  }
  else if (tid < 104){ u=0; l=tid-4;   act=false; }   // idle quad (aligned)
  else if (tid < 304){ u=1; l=tid-104; act=true;  }   // 104 = 8*13: oct-aligned
  else if (tid < 504){ u=2; l=tid-304; act=true;  }   // 304 = 8*38
  else               { u=2; l=tid-312; act=false; }   // idle oct (aligned)

  int gq, rp, g3, lv;
  if (u==0){ gq = l&3; rp = l>>2; g3 = gq; lv = 0; }
  else     { gq = l&7; rp = l>>3; g3 = gq&3; lv = (u==1) ? (gq<4?0:1) : (gq<4?1:2); }
  const int r = 4*rp + g3;                 // output row owned after reduce
  const bool odd = tid & 1, hi = tid & 2;

  // per-lane weights: 4 rows x 28 cols = 28 float4 (112 VGPRs), j-major.
  // Volatile asm loads -> non-rematerializable, forced live in registers.
  v4f w4[28];
  {
    int ubase = (u==0) ? 0 : (u==1) ? 11200 : 33600;
    const float* wp = ws + OFF_WU + ubase + l*112;
    #pragma unroll
    for (int i=0;i<28;i++){
      asm volatile("global_load_dwordx4 %0, %1, off"
                   : "=v"(w4[i]) : "v"(wp + 4*i) : "memory");
    }
    asm volatile("s_waitcnt vmcnt(0)" ::: "memory");
  }
  const float br = (u==0) ? 0.f : ws[OFF_BS + (u-1)*100 + r];

  for (int i=tid;i<6200;i+=512) ep_s[i] = ws[OFF_EP+i];
  for (int i=tid;i<TT;i+=512){
    ids_s[0][i] = ids[(size_t)bA*TT + i];
    ids_s[1][i] = ids[(size_t)bB*TT + i];
  }
  for (int i=tid;i<2*2*3*112;i+=512) ((float*)hs)[i] = 0.f;
  __syncthreads();

  // read bases (float4 units): [(p*2+X)*3+lv]*28 + 7*g3 ; parity stride 168
  const float4* h4 = (const float4*)hs;
  const int iA = lv*28 + 7*g3;
  const int iB = 84 + lv*28 + 7*g3;
  float* hw = (float*)hs;

  int idnA = 0, idnB = 0; float epxA = 0.f, epxB = 0.f;
  if (u == 0){
    epxA = ep_s[ids_s[0][0]*HH + l];
    epxB = ep_s[ids_s[1][0]*HH + l];
    idnA = ids_s[0][1]; idnB = ids_s[1][1];
  }
  const int X  = gq >> 2;                  // batch handled in epilogue (u1/u2)
  const int bX = X ? bB : bA;
  float* stp = buf + (size_t)bX*TT*HH + r; // [B][T][H]

  for (int s = 0; s < TT + 2; ++s){
    const int po = (s & 1) ? 0 : 168;      // read parity offset (float4)
    const int wo = (s & 1) ? 672 : 0;      // write parity offset (float)

    v2f aA0={0.f,0.f}, aA1={0.f,0.f}, aA2={0.f,0.f}, aA3={0.f,0.f};
    v2f aB0={0.f,0.f}, aB1={0.f,0.f}, aB2={0.f,0.f}, aB3={0.f,0.f};
    const float4* pA = h4 + (iA + po);
    const float4* pB = h4 + (iB + po);
    #pragma unroll
    for (int i=0;i<7;i++){
      float4 ha = pA[i];
      float4 hb = pB[i];
      v2f h0 = {ha.x,ha.y}, h1 = {ha.z,ha.w};
      v2f g0 = {hb.x,hb.y}, g1 = {hb.z,hb.w};
      v4f wv0 = w4[i], wv1 = w4[7+i], wv2 = w4[14+i], wv3 = w4[21+i];
      v2f w00={wv0.x,wv0.y}, w01={wv0.z,wv0.w};
      v2f w10={wv1.x,wv1.y}, w11={wv1.z,wv1.w};
      v2f w20={wv2.x,wv2.y}, w21={wv2.z,wv2.w};
      v2f w30={wv3.x,wv3.y}, w31={wv3.z,wv3.w};
      aA0 = __builtin_elementwise_fma(w00,h0,aA0); aA0 = __builtin_elementwise_fma(w01,h1,aA0);
      aA1 = __builtin_elementwise_fma(w10,h0,aA1); aA1 = __builtin_elementwise_fma(w11,h1,aA1);
      aA2 = __builtin_elementwise_fma(w20,h0,aA2); aA2 = __builtin_elementwise_fma(w21,h1,aA2);
      aA3 = __builtin_elementwise_fma(w30,h0,aA3); aA3 = __builtin_elementwise_fma(w31,h1,aA3);
      aB0 = __builtin_elementwise_fma(w00,g0,aB0); aB0 = __builtin_elementwise_fma(w01,g1,aB0);
      aB1 = __builtin_elementwise_fma(w10,g0,aB1); aB1 = __builtin_elementwise_fma(w11,g1,aB1);
      aB2 = __builtin_elementwise_fma(w20,g0,aB2); aB2 = __builtin_elementwise_fma(w21,g1,aB2);
      aB3 = __builtin_elementwise_fma(w30,g0,aB3); aB3 = __builtin_elementwise_fma(w31,g1,aB3);
    }
    float zA = quad_txr(aA0.x+aA0.y, aA1.x+aA1.y, aA2.x+aA2.y, aA3.x+aA3.y, odd, hi);
    float zB = quad_txr(aB0.x+aB0.y, aB1.x+aB1.y, aB2.x+aB2.y, aB3.x+aB3.y, odd, hi);
    if (u){
      zA += swz_xor4(zA);
      zB += swz_xor4(zB);
    }

    if (u == 0){
      if (act && s < TT){
        float hA = tanh_fast(epxA + zA);
        float hB = tanh_fast(epxB + zB);
        hw[wo + l]       = hA;             // [p][A][0][l]
        hw[wo + 336 + l] = hB;             // [p][B][0][l]
        if (s == TT-1){
          hid[(size_t)bA*HH + l] = hA;
          hid[(size_t)bB*HH + l] = hB;
        }
        epxA = ep_s[idnA*HH + l];
        epxB = ep_s[idnB*HH + l];
        int nid = (s+2 < TT) ? s+2 : TT-1;
        idnA = ids_s[0][nid]; idnB = ids_s[1][nid];
      }
    } else {
      float z = X ? zB : zA;
      bool on = (u == 1) ? ((unsigned)(s-1) < TT) : (s >= 2);
      if (act && on){
        float hv = tanh_fast(z + br);
        hw[wo + X*336 + u*112 + r] = hv;   // [p][X][u][r]
        if (u == 2){ *stp = hv; stp += HH; }
        if (u == 1 && s == TT)     hid[((size_t)BB   + bX)*HH + r] = hv;
        if (u == 2 && s == TT+1)   hid[((size_t)2*BB + bX)*HH + r] = hv;
      }
    }

    asm volatile("s_waitcnt lgkmcnt(0)" ::: "memory");
    __builtin_amdgcn_s_barrier();
    asm volatile("" ::: "memory");
  }
}

// Decoder: WG = (b, 128 consecutive t). buf is [B][T][H] -> fully linear reads.
__global__ __launch_bounds__(128) void dec_kernel(
    const float* __restrict__ buf, const float* __restrict__ wdt,
    const float* __restrict__ bdp, float* __restrict__ out)
{
  __shared__ float rt[100*129];
  const int tid = threadIdx.x;
  const int wg  = blockIdx.x;
  const int bb  = wg >> 3;
  const int t0  = (wg & 7) * 128;
  const float4* b4 = (const float4*)buf;
  const size_t rb = ((size_t)bb*TT + t0)*25;

  #pragma unroll
  for (int j=0;j<25;j++){
    int f = j*128 + tid;
    int i = f/25, c = f%25;
    float4 v = b4[rb + f];
    rt[(4*c+0)*129 + i] = v.x;
    rt[(4*c+1)*129 + i] = v.y;
    rt[(4*c+2)*129 + i] = v.z;
    rt[(4*c+3)*129 + i] = v.w;
  }
  __syncthreads();

  v4f acc[16];
  const v4f* bd4 = (const v4f*)bdp;
  #pragma unroll
  for (int j=0;j<16;j++) acc[j] = bd4[j];

  for (int h=0; h<HH; h++){
    float rv = rt[h*129 + tid];
    v4f rv4 = {rv, rv, rv, rv};
    const v4f* w4g = (const v4f*)(wdt + h*64);
    #pragma unroll
    for (int j=0;j<16;j++) acc[j] = __builtin_elementwise_fma(w4g[j], rv4, acc[j]);
  }

  float2* o2 = (float2*)(out + ((size_t)bb*TT + t0 + tid)*VV);
  #pragma unroll
  for (int j=0;j<15;j++){
    o2[2*j]   = make_float2(acc[j].x, acc[j].y);
    o2[2*j+1] = make_float2(acc[j].z, acc[j].w);
  }
  o2[30] = make_float2(acc[15].x, acc[15].y);   // v=60,61
}

extern "C" void kernel_launch(void* const* d_in, const int* in_sizes, int n_in,
                              void* d_out, int out_size, void* d_ws, size_t ws_size,
                              hipStream_t stream)
{
  const int*   ids   = (const int*)d_in[0];
  const float* emb   = (const float*)d_in[1];
  const float* W_ih  = (const float*)d_in[2];
  const float* W_hh  = (const float*)d_in[3];
  const float* b_ih  = (const float*)d_in[4];
  const float* b_hh  = (const float*)d_in[5];
  const float* W_dec = (const float*)d_in[6];
  const float* b_dec = (const float*)d_in[7];
  float* out = (float*)d_out;
  float* ws  = (float*)d_ws;
  float* buf = ws;                 // [B][T][H] fp32, ~210 MB
  float* hid = out + BTV;

  prep_kernel<<<269, 256, 0, stream>>>(emb, W_ih, W_hh, b_ih, b_hh, W_dec, b_dec, ws);
  fused_rnn <<<256, 512, 0, stream>>>(ids, ws, buf, hid);
  dec_kernel<<<4096, 128, 0, stream>>>(buf, ws+OFF_WDT, ws+OFF_BDP, out);
}